// Round 7
// baseline (119.826 us; speedup 1.0000x reference)
//
#include <hip/hip_runtime.h>
#include <math.h>

#define BLOCK 256
#define HF 63                      // floats per hand
#define TILE_F (BLOCK * HF)        // 16128 floats per tile (64512 B)
#define TILE_V4 (TILE_F / 4)       // 4032 float4s

__device__ __forceinline__ float rsqf(float x)  { return __builtin_amdgcn_rsqf(x); }
__device__ __forceinline__ float sqtf(float x)  { return __builtin_amdgcn_sqrtf(x); }

__global__ __launch_bounds__(BLOCK, 2)
void kin_fwd(const float* __restrict__ joints,
             const float* __restrict__ tempJ,
             float* __restrict__ out,
             int n_total)
{
    constexpr int CHILD[15]  = {2,3,17, 5,6,18, 8,9,20, 11,12,19, 14,15,16};
    constexpr int PARENT[15] = {1,2,3, 4,5,6, 7,8,9, 10,11,12, 13,14,15};
    constexpr int GPID[15]   = {0,1,2, 0,4,5, 0,7,8, 0,10,11, 0,13,14};
    constexpr int PALMNZ[5]  = {1,4,7,10,13};   // palm joints minus wrist (J[0]=T[0]=0 after centering)

    __shared__ float lds[TILE_F];          // one buffer reused: tempJ -> joints -> out

    const int tid = threadIdx.x;
    const int n   = blockIdx.x * BLOCK + tid;
    const long long tileBase = (long long)blockIdx.x * TILE_F;
    const long long totalF   = (long long)n_total * HF;
    const bool fullTile = (tileBase + TILE_F) <= totalF;
    const bool active = (n < n_total);

    // ---- stage tempJ tile (coalesced float4) + PREFETCH joints tile into regs ----
    float4 jr[16];
    if (fullTile) {
        const float4* gt = (const float4*)(tempJ + tileBase);
        const float4* gj = (const float4*)(joints + tileBase);
        float4* l4 = (float4*)lds;
#pragma unroll
        for (int r = 0; r < 16; ++r) {
            const int idx = r * BLOCK + tid;
            if (idx < TILE_V4) l4[idx] = gt[idx];
        }
#pragma unroll
        for (int r = 0; r < 16; ++r) {          // prefetch: loads in flight during T phase
            const int idx = r * BLOCK + tid;
            if (idx < TILE_V4) jr[r] = gj[idx];
        }
    } else {
        for (int idx = tid; idx < TILE_F; idx += BLOCK) {
            const long long g = tileBase + idx;
            lds[idx] = (g < totalF) ? tempJ[g] : 0.f;
        }
    }
    __syncthreads();

    float T[21][3];
    float blen2[15];               // squared template bone lengths

    if (active) {
        const float* tl = lds + tid * HF;
#pragma unroll
        for (int k = 0; k < 21; ++k) {
            T[k][0] = tl[3*k+0];
            T[k][1] = tl[3*k+1];
            T[k][2] = tl[3*k+2];
        }
        const float ox = T[0][0], oy = T[0][1], oz = T[0][2];
#pragma unroll
        for (int k = 0; k < 21; ++k) { T[k][0] -= ox; T[k][1] -= oy; T[k][2] -= oz; }

#pragma unroll
        for (int i = 0; i < 15; ++i) {
            const float dx = T[CHILD[i]][0] - T[PARENT[i]][0];
            const float dy = T[CHILD[i]][1] - T[PARENT[i]][1];
            const float dz = T[CHILD[i]][2] - T[PARENT[i]][2];
            blen2[i] = dx*dx + dy*dy + dz*dz;
        }
    }
    __syncthreads();   // all reads of tempJ tile done

    // ---- dump prefetched joints tile to LDS (stays LDS-resident; each elem read once) ----
    if (fullTile) {
        float4* l4 = (float4*)lds;
#pragma unroll
        for (int r = 0; r < 16; ++r) {
            const int idx = r * BLOCK + tid;
            if (idx < TILE_V4) l4[idx] = jr[r];
        }
    } else {
        for (int idx = tid; idx < TILE_F; idx += BLOCK) {
            const long long g = tileBase + idx;
            lds[idx] = (g < totalF) ? joints[g] : 0.f;
        }
    }
    __syncthreads();

    float wx = 0.f, wy = 0.f, wz = 0.f;

    if (active) {
        const float* jl = lds + tid * HF;
        wx = jl[0]; wy = jl[1]; wz = jl[2];
        // centered joint accessor (LDS-resident, each element consumed once)
        #define JLC(k,d) (jl[3*(k)+(d)] - ((d)==0 ? wx : ((d)==1 ? wy : wz)))

        // H = sum_palm T[k] * J[k]^T  (Kabsch: R @ T ~= J on palm; k=0 term is 0)
        float H[3][3] = {{0.f,0.f,0.f},{0.f,0.f,0.f},{0.f,0.f,0.f}};
#pragma unroll
        for (int p = 0; p < 5; ++p) {
            const int k = PALMNZ[p];
            const float jx = JLC(k,0), jy = JLC(k,1), jz = JLC(k,2);
            H[0][0] += T[k][0]*jx; H[0][1] += T[k][0]*jy; H[0][2] += T[k][0]*jz;
            H[1][0] += T[k][1]*jx; H[1][1] += T[k][1]*jy; H[1][2] += T[k][1]*jz;
            H[2][0] += T[k][2]*jx; H[2][1] += T[k][2]*jy; H[2][2] += T[k][2]*jz;
        }

        // A = H^T H  (symmetric PSD)
        float A[3][3];
#pragma unroll
        for (int i = 0; i < 3; ++i)
#pragma unroll
            for (int j = 0; j < 3; ++j)
                A[i][j] = H[0][i]*H[0][j] + H[1][i]*H[1][j] + H[2][i]*H[2][j];

        // ---- Cardano eigenvalues of A ----
        const float q   = (A[0][0] + A[1][1] + A[2][2]) * (1.f/3.f);
        const float a00 = A[0][0]-q, a11 = A[1][1]-q, a22 = A[2][2]-q;
        const float a01 = A[0][1], a02 = A[0][2], a12 = A[1][2];
        const float p1  = a01*a01 + a02*a02 + a12*a12;
        const float p2s = a00*a00 + a11*a11 + a22*a22 + 2.f*p1;
        const float p26 = p2s*(1.f/6.f) + 1e-30f;
        const float ip  = rsqf(p26);         // 1/p
        const float p   = p26 * ip;          // p = sqrt(p2/6)
        const float detC =
            a00*(a11*a22 - a12*a12) - a01*(a01*a22 - a12*a02) + a02*(a01*a12 - a11*a02);
        float r = 0.5f * detC * ip*ip*ip;
        r = fminf(1.f, fmaxf(-1.f, r));
        const float phi_rev = acosf(r) * 0.05305164769729845f;   // acos(r)/3 in revolutions
        const float cph = __builtin_amdgcn_cosf(phi_rev);
        const float sph = __builtin_amdgcn_sinf(phi_rev);
        const float e1 = q + 2.f*p*cph;                          // largest
        const float e3 = q - p*(cph + 1.7320508075688772f*sph);  // smallest
        const float e2 = 3.f*q - e1 - e3;                        // middle

        // ---- robust eigvec for the MOST ISOLATED eigenvalue ----
        const float gap12 = e1 - e2, gap23 = e2 - e3;
        const bool isoTop = (gap12 >= gap23);
        const float sAB = isoTop ? (e2 + e3) : (e1 + e2);
        const float pAB = isoTop ? (e2 * e3) : (e1 * e2);

        // A2 = A*A (symmetric, 6 entries)
        const float A2_00 = A[0][0]*A[0][0] + A[0][1]*A[0][1] + A[0][2]*A[0][2];
        const float A2_01 = A[0][0]*A[0][1] + A[0][1]*A[1][1] + A[0][2]*A[1][2];
        const float A2_02 = A[0][0]*A[0][2] + A[0][1]*A[1][2] + A[0][2]*A[2][2];
        const float A2_11 = A[0][1]*A[0][1] + A[1][1]*A[1][1] + A[1][2]*A[1][2];
        const float A2_12 = A[0][1]*A[0][2] + A[1][1]*A[1][2] + A[1][2]*A[2][2];
        const float A2_22 = A[0][2]*A[0][2] + A[1][2]*A[1][2] + A[2][2]*A[2][2];

        const float m00 = A2_00 - sAB*A[0][0] + pAB;
        const float m01 = A2_01 - sAB*A[0][1];
        const float m02 = A2_02 - sAB*A[0][2];
        const float m11 = A2_11 - sAB*A[1][1] + pAB;
        const float m12 = A2_12 - sAB*A[1][2];
        const float m22 = A2_22 - sAB*A[2][2] + pAB;

        const float n0c = m00*m00 + m01*m01 + m02*m02;
        const float n1c = m01*m01 + m11*m11 + m12*m12;
        const float n2c = m02*m02 + m12*m12 + m22*m22;
        float vx = m00, vy = m01, vz = m02, nb = n0c;
        if (n1c > nb) { vx = m01; vy = m11; vz = m12; nb = n1c; }
        if (n2c > nb) { vx = m02; vy = m12; vz = m22; nb = n2c; }
        if (nb < 1e-24f) { vx = 1.f; vy = 0.f; vz = 0.f; }   // fully-degenerate fallback
        {
            const float invv = rsqf(vx*vx + vy*vy + vz*vz + 1e-35f);
            vx *= invv; vy *= invv; vz *= invv;
        }

        // orthonormal basis (b1,b2) of plane ⊥ v_iso
        float hx, hy, hz;
        {
            const float axv = fabsf(vx), ayv = fabsf(vy), azv = fabsf(vz);
            if (axv <= ayv && axv <= azv)      { hx = 0.f;  hy = vz;  hz = -vy; }
            else if (ayv <= azv)               { hx = -vz;  hy = 0.f; hz = vx;  }
            else                               { hx = vy;   hy = -vx; hz = 0.f; }
        }
        const float invh = rsqf(hx*hx + hy*hy + hz*hz + 1e-35f);
        const float b1x = hx*invh, b1y = hy*invh, b1z = hz*invh;
        const float b2x = vy*b1z - vz*b1y;
        const float b2y = vz*b1x - vx*b1z;
        const float b2z = vx*b1y - vy*b1x;

        // 2x2 restriction of A to the plane: B = [alpha beta; beta gamma]
        const float Ab1x = A[0][0]*b1x + A[0][1]*b1y + A[0][2]*b1z;
        const float Ab1y = A[0][1]*b1x + A[1][1]*b1y + A[1][2]*b1z;
        const float Ab1z = A[0][2]*b1x + A[1][2]*b1y + A[2][2]*b1z;
        const float Ab2x = A[0][0]*b2x + A[0][1]*b2y + A[0][2]*b2z;
        const float Ab2y = A[0][1]*b2x + A[1][1]*b2y + A[1][2]*b2z;
        const float Ab2z = A[0][2]*b2x + A[1][2]*b2y + A[2][2]*b2z;
        const float alpha = b1x*Ab1x + b1y*Ab1y + b1z*Ab1z;
        const float beta  = b2x*Ab1x + b2y*Ab1y + b2z*Ab1z;
        const float gamma = b2x*Ab2x + b2y*Ab2y + b2z*Ab2z;

        // top-of-plane eigenvector: t = (beta, root - dif) in (b1,b2) coords
        const float difq  = 0.5f*(alpha - gamma);
        const float rootq = sqtf(difq*difq + beta*beta);
        float tx = beta, ty = rootq - difq;
        if (tx*tx + ty*ty < 1e-30f) { tx = 1.f; ty = 0.f; }  // degenerate plane: any basis
        const float invt = rsqf(tx*tx + ty*ty + 1e-35f);
        const float ctx = tx*invt, cty = ty*invt;
        const float wpx = ctx*b1x + cty*b2x;
        const float wpy = ctx*b1y + cty*b2y;
        const float wpz = ctx*b1z + cty*b2z;
        // in-plane complement (sign irrelevant: u's inherit v-signs through GS)
        const float wmx = vy*wpz - vz*wpy;
        const float wmy = vz*wpx - vx*wpz;
        const float wmz = vx*wpy - vy*wpx;

        // assign by descending eigenvalue
        const float v1x = isoTop ? vx  : wpx;
        const float v1y = isoTop ? vy  : wpy;
        const float v1z = isoTop ? vz  : wpz;
        const float v2x = isoTop ? wpx : wmx;
        const float v2y = isoTop ? wpy : wmy;
        const float v2z = isoTop ? wpz : wmz;
        // v3 = v1 x v2  (det V = +1 => Kabsch sign folds to +1 with det U = +1)
        const float v3x = v1y*v2z - v1z*v2y;
        const float v3y = v1z*v2x - v1x*v2z;
        const float v3z = v1x*v2y - v1y*v2x;

        // U via Gram-Schmidt on H*V (no 1/sigma anywhere)
        float R[3][3];
        {
            const float w1x = H[0][0]*v1x + H[0][1]*v1y + H[0][2]*v1z;
            const float w1y = H[1][0]*v1x + H[1][1]*v1y + H[1][2]*v1z;
            const float w1z = H[2][0]*v1x + H[2][1]*v1y + H[2][2]*v1z;
            const float in1 = rsqf(w1x*w1x + w1y*w1y + w1z*w1z + 1e-35f);
            const float u1x = w1x*in1, u1y = w1y*in1, u1z = w1z*in1;

            float w2x = H[0][0]*v2x + H[0][1]*v2y + H[0][2]*v2z;
            float w2y = H[1][0]*v2x + H[1][1]*v2y + H[1][2]*v2z;
            float w2z = H[2][0]*v2x + H[2][1]*v2y + H[2][2]*v2z;
            const float dp = u1x*w2x + u1y*w2y + u1z*w2z;
            w2x -= dp*u1x; w2y -= dp*u1y; w2z -= dp*u1z;
            const float in2 = rsqf(w2x*w2x + w2y*w2y + w2z*w2z + 1e-35f);
            const float u2x = w2x*in2, u2y = w2y*in2, u2z = w2z*in2;

            const float u3x = u1y*u2z - u1z*u2y;
            const float u3y = u1z*u2x - u1x*u2z;
            const float u3z = u1x*u2y - u1y*u2x;

            R[0][0] = v1x*u1x + v2x*u2x + v3x*u3x;
            R[0][1] = v1x*u1y + v2x*u2y + v3x*u3y;
            R[0][2] = v1x*u1z + v2x*u2z + v3x*u3z;
            R[1][0] = v1y*u1x + v2y*u2x + v3y*u3x;
            R[1][1] = v1y*u1y + v2y*u2y + v3y*u3y;
            R[1][2] = v1y*u1z + v2y*u2z + v3y*u3z;
            R[2][0] = v1z*u1x + v2z*u2x + v3z*u3x;
            R[2][1] = v1z*u1y + v2z*u2y + v3z*u3y;
            R[2][2] = v1z*u1z + v2z*u2z + v3z*u3z;
        }

        // T = R @ T
#pragma unroll
        for (int k = 0; k < 21; ++k) {
            const float x = T[k][0], y = T[k][1], z = T[k][2];
            T[k][0] = R[0][0]*x + R[0][1]*y + R[0][2]*z;
            T[k][1] = R[1][0]*x + R[1][1]*y + R[1][2]*z;
            T[k][2] = R[2][0]*x + R[2][1]*y + R[2][2]*z;
        }

        // kinematic chain — LEVEL-MAJOR: 5 independent fingers in flight per level
#pragma unroll
        for (int k2 = 0; k2 < 3; ++k2) {
#pragma unroll
            for (int f = 0; f < 5; ++f) {
                const int i = f*3 + k2;
                const int ch = CHILD[i], pa = PARENT[i], gp = GPID[i];

                // bone-length renorm: T[ch] = T[pa] + v1 * sqrt(blen2/d2)
                const float v1xc = JLC(ch,0) - T[pa][0];
                const float v1yc = JLC(ch,1) - T[pa][1];
                const float v1zc = JLC(ch,2) - T[pa][2];
                const float d2  = v1xc*v1xc + v1yc*v1yc + v1zc*v1zc;
                const float b2  = blen2[i];
                const float sc  = b2 * rsqf(b2*d2 + 1e-30f);   // sqrt(b2)/sqrt(d2)
                const float vbx = v1xc*sc, vby = v1yc*sc, vbz = v1zc*sc;

                const float v0x = T[pa][0] - T[gp][0];
                const float v0y = T[pa][1] - T[gp][1];
                const float v0z = T[pa][2] - T[gp][2];

                const float crx = v0y*vbz - v0z*vby;
                const float cry = v0z*vbx - v0x*vbz;
                const float crz = v0x*vby - v0y*vbx;
                const float s2  = crx*crx + cry*cry + crz*crz;
                const float c   = v0x*vbx + v0y*vby + v0z*vbz;

                // delta = clip(ang,0,pi/2) - ang; nonzero only when c < 0
                const float invr  = rsqf(s2 + c*c + 1e-35f);
                const float sainv = rsqf(s2 + 1e-35f);
                const float s     = s2 * sainv;              // sqrt(s2)
                const float cosd  = (c < 0.f) ? s*invr : 1.f;
                const float sind  = (c < 0.f) ? c*invr : 0.f;

                const float ax = crx*sainv, ay = cry*sainv, az = crz*sainv;
                const float cxx = ay*vbz - az*vby;
                const float cxy = az*vbx - ax*vbz;
                const float cxz = ax*vby - ay*vbx;
                // axis . vb == 0 exactly (axis ∝ v0 x vb) -> omc term dropped
                T[ch][0] = vbx*cosd + cxx*sind + T[pa][0];
                T[ch][1] = vby*cosd + cxy*sind + T[pa][1];
                T[ch][2] = vbz*cosd + cxz*sind + T[pa][2];
            }
        }
        #undef JLC

        // write own result region (only this thread ever reads/wrote this region)
        float* ol = lds + tid * HF;
#pragma unroll
        for (int k = 0; k < 21; ++k) {
            ol[3*k+0] = wx + T[k][0];
            ol[3*k+1] = wy + T[k][1];
            ol[3*k+2] = wz + T[k][2];
        }
    }
    __syncthreads();

    // ---- coalesced float4 store ----
    if (fullTile) {
        float4* g4 = (float4*)(out + tileBase);
        const float4* l4 = (const float4*)lds;
        for (int idx = tid; idx < TILE_V4; idx += BLOCK) g4[idx] = l4[idx];
    } else {
        for (int idx = tid; idx < TILE_F; idx += BLOCK) {
            const long long g = tileBase + idx;
            if (g < totalF) out[g] = lds[idx];
        }
    }
}

extern "C" void kernel_launch(void* const* d_in, const int* in_sizes, int n_in,
                              void* d_out, int out_size, void* d_ws, size_t ws_size,
                              hipStream_t stream)
{
    const float* joints = (const float*)d_in[0];
    const float* tempJ  = (const float*)d_in[1];
    float* out          = (float*)d_out;

    const int n_total = in_sizes[0] / 63;   // (N,21,3) flattened
    const int grid = (n_total + BLOCK - 1) / BLOCK;
    kin_fwd<<<grid, BLOCK, 0, stream>>>(joints, tempJ, out, n_total);
}

// Round 8
// 110.786 us; speedup vs baseline: 1.0816x; 1.0816x over previous
//
#include <hip/hip_runtime.h>
#include <math.h>

#define BLOCK 256
#define HF 63                      // floats per hand
#define TILE_F (BLOCK * HF)        // 16128 floats per tile (64512 B)
#define TILE_V4 (TILE_F / 4)       // 4032 float4s

__device__ __forceinline__ float rsqf(float x)  { return __builtin_amdgcn_rsqf(x); }
__device__ __forceinline__ float sqtf(float x)  { return __builtin_amdgcn_sqrtf(x); }

__global__ __launch_bounds__(BLOCK, 2)
void kin_fwd(const float* __restrict__ joints,
             const float* __restrict__ tempJ,
             float* __restrict__ out,
             int n_total)
{
    constexpr int CHILD[15]  = {2,3,17, 5,6,18, 8,9,20, 11,12,19, 14,15,16};
    constexpr int PARENT[15] = {1,2,3, 4,5,6, 7,8,9, 10,11,12, 13,14,15};
    constexpr int GPID[15]   = {0,1,2, 0,4,5, 0,7,8, 0,10,11, 0,13,14};
    constexpr int PALMNZ[5]  = {1,4,7,10,13};   // palm minus wrist (J[0]=T[0]=0 after centering)

    __shared__ float lds[TILE_F];          // one buffer reused: tempJ -> joints -> out

    const int tid = threadIdx.x;
    const int n   = blockIdx.x * BLOCK + tid;
    const long long tileBase = (long long)blockIdx.x * TILE_F;
    const long long totalF   = (long long)n_total * HF;
    const bool fullTile = (tileBase + TILE_F) <= totalF;
    const bool active = (n < n_total);

    // ---- stage tempJ tile (coalesced float4) ----
    if (fullTile) {
        const float4* g4 = (const float4*)(tempJ + tileBase);
        float4* l4 = (float4*)lds;
        for (int idx = tid; idx < TILE_V4; idx += BLOCK) l4[idx] = g4[idx];
    } else {
        for (int idx = tid; idx < TILE_F; idx += BLOCK) {
            const long long g = tileBase + idx;
            lds[idx] = (g < totalF) ? tempJ[g] : 0.f;
        }
    }
    __syncthreads();

    float T[21][3];
    float blen2[15];               // squared template bone lengths

    if (active) {
        const float* tl = lds + tid * HF;
#pragma unroll
        for (int k = 0; k < 21; ++k) {
            T[k][0] = tl[3*k+0];
            T[k][1] = tl[3*k+1];
            T[k][2] = tl[3*k+2];
        }
        const float ox = T[0][0], oy = T[0][1], oz = T[0][2];
#pragma unroll
        for (int k = 0; k < 21; ++k) { T[k][0] -= ox; T[k][1] -= oy; T[k][2] -= oz; }

#pragma unroll
        for (int i = 0; i < 15; ++i) {
            const float dx = T[CHILD[i]][0] - T[PARENT[i]][0];
            const float dy = T[CHILD[i]][1] - T[PARENT[i]][1];
            const float dz = T[CHILD[i]][2] - T[PARENT[i]][2];
            blen2[i] = dx*dx + dy*dy + dz*dz;
        }
    }
    __syncthreads();   // all reads of tempJ tile done

    // ---- stage joints tile (coalesced float4) ----
    if (fullTile) {
        const float4* g4 = (const float4*)(joints + tileBase);
        float4* l4 = (float4*)lds;
        for (int idx = tid; idx < TILE_V4; idx += BLOCK) l4[idx] = g4[idx];
    } else {
        for (int idx = tid; idx < TILE_F; idx += BLOCK) {
            const long long g = tileBase + idx;
            lds[idx] = (g < totalF) ? joints[g] : 0.f;
        }
    }
    __syncthreads();

    float wx = 0.f, wy = 0.f, wz = 0.f;

    if (active) {
        // joints into registers, centered at wrist (R6-proven: no spill at this live set)
        float Jl[21][3];
        {
            const float* jl = lds + tid * HF;
            wx = jl[0]; wy = jl[1]; wz = jl[2];
#pragma unroll
            for (int k = 0; k < 21; ++k) {
                Jl[k][0] = jl[3*k+0] - wx;
                Jl[k][1] = jl[3*k+1] - wy;
                Jl[k][2] = jl[3*k+2] - wz;
            }
        }

        // H = sum_palm T[k] * J[k]^T  (wrist term is exactly zero)
        float H[3][3] = {{0.f,0.f,0.f},{0.f,0.f,0.f},{0.f,0.f,0.f}};
#pragma unroll
        for (int p = 0; p < 5; ++p) {
            const int k = PALMNZ[p];
#pragma unroll
            for (int i = 0; i < 3; ++i)
#pragma unroll
                for (int j = 0; j < 3; ++j)
                    H[i][j] += T[k][i] * Jl[k][j];
        }

        // A = H^T H  (symmetric PSD)
        float A[3][3];
#pragma unroll
        for (int i = 0; i < 3; ++i)
#pragma unroll
            for (int j = 0; j < 3; ++j)
                A[i][j] = H[0][i]*H[0][j] + H[1][i]*H[1][j] + H[2][i]*H[2][j];

        // ---- Cardano eigenvalues of A ----
        const float q   = (A[0][0] + A[1][1] + A[2][2]) * (1.f/3.f);
        const float a00 = A[0][0]-q, a11 = A[1][1]-q, a22 = A[2][2]-q;
        const float a01 = A[0][1], a02 = A[0][2], a12 = A[1][2];
        const float p1  = a01*a01 + a02*a02 + a12*a12;
        const float p2s = a00*a00 + a11*a11 + a22*a22 + 2.f*p1;
        const float p26 = p2s*(1.f/6.f) + 1e-30f;
        const float ip  = rsqf(p26);         // 1/p
        const float p   = p26 * ip;          // p = sqrt(p2/6)
        const float detC =
            a00*(a11*a22 - a12*a12) - a01*(a01*a22 - a12*a02) + a02*(a01*a12 - a11*a02);
        float r = 0.5f * detC * ip*ip*ip;
        r = fminf(1.f, fmaxf(-1.f, r));
        const float phi_rev = acosf(r) * 0.05305164769729845f;   // acos(r)/3 in revolutions
        const float cph = __builtin_amdgcn_cosf(phi_rev);
        const float sph = __builtin_amdgcn_sinf(phi_rev);
        const float e1 = q + 2.f*p*cph;                          // largest
        const float e3 = q - p*(cph + 1.7320508075688772f*sph);  // smallest
        const float e2 = 3.f*q - e1 - e3;                        // middle

        // ---- robust eigvec for the MOST ISOLATED eigenvalue ----
        const float gap12 = e1 - e2, gap23 = e2 - e3;
        const bool isoTop = (gap12 >= gap23);
        const float sAB = isoTop ? (e2 + e3) : (e1 + e2);
        const float pAB = isoTop ? (e2 * e3) : (e1 * e2);

        // A2 = A*A (symmetric, 6 entries)
        const float A2_00 = A[0][0]*A[0][0] + A[0][1]*A[0][1] + A[0][2]*A[0][2];
        const float A2_01 = A[0][0]*A[0][1] + A[0][1]*A[1][1] + A[0][2]*A[1][2];
        const float A2_02 = A[0][0]*A[0][2] + A[0][1]*A[1][2] + A[0][2]*A[2][2];
        const float A2_11 = A[0][1]*A[0][1] + A[1][1]*A[1][1] + A[1][2]*A[1][2];
        const float A2_12 = A[0][1]*A[0][2] + A[1][1]*A[1][2] + A[1][2]*A[2][2];
        const float A2_22 = A[0][2]*A[0][2] + A[1][2]*A[1][2] + A[2][2]*A[2][2];

        const float m00 = A2_00 - sAB*A[0][0] + pAB;
        const float m01 = A2_01 - sAB*A[0][1];
        const float m02 = A2_02 - sAB*A[0][2];
        const float m11 = A2_11 - sAB*A[1][1] + pAB;
        const float m12 = A2_12 - sAB*A[1][2];
        const float m22 = A2_22 - sAB*A[2][2] + pAB;

        const float n0c = m00*m00 + m01*m01 + m02*m02;
        const float n1c = m01*m01 + m11*m11 + m12*m12;
        const float n2c = m02*m02 + m12*m12 + m22*m22;
        float vx = m00, vy = m01, vz = m02, nb = n0c;
        if (n1c > nb) { vx = m01; vy = m11; vz = m12; nb = n1c; }
        if (n2c > nb) { vx = m02; vy = m12; vz = m22; nb = n2c; }
        if (nb < 1e-24f) { vx = 1.f; vy = 0.f; vz = 0.f; }   // fully-degenerate fallback
        {
            const float invv = rsqf(vx*vx + vy*vy + vz*vz + 1e-35f);
            vx *= invv; vy *= invv; vz *= invv;
        }

        // orthonormal basis (b1,b2) of plane ⊥ v_iso
        float hx, hy, hz;
        {
            const float axv = fabsf(vx), ayv = fabsf(vy), azv = fabsf(vz);
            if (axv <= ayv && axv <= azv)      { hx = 0.f;  hy = vz;  hz = -vy; }
            else if (ayv <= azv)               { hx = -vz;  hy = 0.f; hz = vx;  }
            else                               { hx = vy;   hy = -vx; hz = 0.f; }
        }
        const float invh = rsqf(hx*hx + hy*hy + hz*hz + 1e-35f);
        const float b1x = hx*invh, b1y = hy*invh, b1z = hz*invh;
        const float b2x = vy*b1z - vz*b1y;
        const float b2y = vz*b1x - vx*b1z;
        const float b2z = vx*b1y - vy*b1x;

        // 2x2 restriction of A to the plane: B = [alpha beta; beta gamma]
        const float Ab1x = A[0][0]*b1x + A[0][1]*b1y + A[0][2]*b1z;
        const float Ab1y = A[0][1]*b1x + A[1][1]*b1y + A[1][2]*b1z;
        const float Ab1z = A[0][2]*b1x + A[1][2]*b1y + A[2][2]*b1z;
        const float Ab2x = A[0][0]*b2x + A[0][1]*b2y + A[0][2]*b2z;
        const float Ab2y = A[0][1]*b2x + A[1][1]*b2y + A[1][2]*b2z;
        const float Ab2z = A[0][2]*b2x + A[1][2]*b2y + A[2][2]*b2z;
        const float alpha = b1x*Ab1x + b1y*Ab1y + b1z*Ab1z;
        const float beta  = b2x*Ab1x + b2y*Ab1y + b2z*Ab1z;
        const float gamma = b2x*Ab2x + b2y*Ab2y + b2z*Ab2z;

        // top-of-plane eigenvector: t = (beta, root - dif) in (b1,b2) coords
        const float difq  = 0.5f*(alpha - gamma);
        const float rootq = sqtf(difq*difq + beta*beta);
        float tx = beta, ty = rootq - difq;
        if (tx*tx + ty*ty < 1e-30f) { tx = 1.f; ty = 0.f; }  // degenerate plane: any basis
        const float invt = rsqf(tx*tx + ty*ty + 1e-35f);
        const float ctx = tx*invt, cty = ty*invt;
        const float wpx = ctx*b1x + cty*b2x;
        const float wpy = ctx*b1y + cty*b2y;
        const float wpz = ctx*b1z + cty*b2z;
        // in-plane complement (sign irrelevant: u's inherit v-signs through GS)
        const float wmx = vy*wpz - vz*wpy;
        const float wmy = vz*wpx - vx*wpz;
        const float wmz = vx*wpy - vy*wpx;

        // assign by descending eigenvalue
        const float v1x = isoTop ? vx  : wpx;
        const float v1y = isoTop ? vy  : wpy;
        const float v1z = isoTop ? vz  : wpz;
        const float v2x = isoTop ? wpx : wmx;
        const float v2y = isoTop ? wpy : wmy;
        const float v2z = isoTop ? wpz : wmz;
        // v3 = v1 x v2  (det V = +1 => Kabsch sign folds to +1 with det U = +1)
        const float v3x = v1y*v2z - v1z*v2y;
        const float v3y = v1z*v2x - v1x*v2z;
        const float v3z = v1x*v2y - v1y*v2x;

        // U via Gram-Schmidt on H*V (no 1/sigma anywhere)
        float R[3][3];
        {
            const float w1x = H[0][0]*v1x + H[0][1]*v1y + H[0][2]*v1z;
            const float w1y = H[1][0]*v1x + H[1][1]*v1y + H[1][2]*v1z;
            const float w1z = H[2][0]*v1x + H[2][1]*v1y + H[2][2]*v1z;
            const float in1 = rsqf(w1x*w1x + w1y*w1y + w1z*w1z + 1e-35f);
            const float u1x = w1x*in1, u1y = w1y*in1, u1z = w1z*in1;

            float w2x = H[0][0]*v2x + H[0][1]*v2y + H[0][2]*v2z;
            float w2y = H[1][0]*v2x + H[1][1]*v2y + H[1][2]*v2z;
            float w2z = H[2][0]*v2x + H[2][1]*v2y + H[2][2]*v2z;
            const float dp = u1x*w2x + u1y*w2y + u1z*w2z;
            w2x -= dp*u1x; w2y -= dp*u1y; w2z -= dp*u1z;
            const float in2 = rsqf(w2x*w2x + w2y*w2y + w2z*w2z + 1e-35f);
            const float u2x = w2x*in2, u2y = w2y*in2, u2z = w2z*in2;

            const float u3x = u1y*u2z - u1z*u2y;
            const float u3y = u1z*u2x - u1x*u2z;
            const float u3z = u1x*u2y - u1y*u2x;

            R[0][0] = v1x*u1x + v2x*u2x + v3x*u3x;
            R[0][1] = v1x*u1y + v2x*u2y + v3x*u3y;
            R[0][2] = v1x*u1z + v2x*u2z + v3x*u3z;
            R[1][0] = v1y*u1x + v2y*u2x + v3y*u3x;
            R[1][1] = v1y*u1y + v2y*u2y + v3y*u3y;
            R[1][2] = v1y*u1z + v2y*u2z + v3y*u3z;
            R[2][0] = v1z*u1x + v2z*u2x + v3z*u3x;
            R[2][1] = v1z*u1y + v2z*u2y + v3z*u3y;
            R[2][2] = v1z*u1z + v2z*u2z + v3z*u3z;
        }

        // T = R @ T
#pragma unroll
        for (int k = 0; k < 21; ++k) {
            const float x = T[k][0], y = T[k][1], z = T[k][2];
            T[k][0] = R[0][0]*x + R[0][1]*y + R[0][2]*z;
            T[k][1] = R[1][0]*x + R[1][1]*y + R[1][2]*z;
            T[k][2] = R[2][0]*x + R[2][1]*y + R[2][2]*z;
        }

        // kinematic chain — LEVEL-MAJOR: 5 independent fingers in flight per level
#pragma unroll
        for (int k2 = 0; k2 < 3; ++k2) {
#pragma unroll
            for (int f = 0; f < 5; ++f) {
                const int i = f*3 + k2;
                const int ch = CHILD[i], pa = PARENT[i], gp = GPID[i];

                // bone-length renorm: T[ch] = T[pa] + v1 * sqrt(blen2/d2)
                const float v1xc = Jl[ch][0] - T[pa][0];
                const float v1yc = Jl[ch][1] - T[pa][1];
                const float v1zc = Jl[ch][2] - T[pa][2];
                const float d2  = v1xc*v1xc + v1yc*v1yc + v1zc*v1zc;
                const float b2  = blen2[i];
                const float sc  = b2 * rsqf(b2*d2 + 1e-30f);   // sqrt(b2)/sqrt(d2)
                const float vbx = v1xc*sc, vby = v1yc*sc, vbz = v1zc*sc;

                const float v0x = T[pa][0] - T[gp][0];
                const float v0y = T[pa][1] - T[gp][1];
                const float v0z = T[pa][2] - T[gp][2];

                const float crx = v0y*vbz - v0z*vby;
                const float cry = v0z*vbx - v0x*vbz;
                const float crz = v0x*vby - v0y*vbx;
                const float s2  = crx*crx + cry*cry + crz*crz;
                const float c   = v0x*vbx + v0y*vby + v0z*vbz;

                // delta = clip(ang,0,pi/2) - ang; nonzero only when c < 0
                const float invr  = rsqf(s2 + c*c + 1e-35f);
                const float sainv = rsqf(s2 + 1e-35f);
                const float s     = s2 * sainv;              // sqrt(s2)
                const float cosd  = (c < 0.f) ? s*invr : 1.f;
                const float sind  = (c < 0.f) ? c*invr : 0.f;

                const float ax = crx*sainv, ay = cry*sainv, az = crz*sainv;
                const float cxx = ay*vbz - az*vby;
                const float cxy = az*vbx - ax*vbz;
                const float cxz = ax*vby - ay*vbx;
                // axis . vb == 0 exactly (axis ∝ v0 x vb) -> omc term dropped
                T[ch][0] = vbx*cosd + cxx*sind + T[pa][0];
                T[ch][1] = vby*cosd + cxy*sind + T[pa][1];
                T[ch][2] = vbz*cosd + cxz*sind + T[pa][2];
            }
        }

        // write own result region (same region this thread read Jl from)
        float* ol = lds + tid * HF;
#pragma unroll
        for (int k = 0; k < 21; ++k) {
            ol[3*k+0] = wx + T[k][0];
            ol[3*k+1] = wy + T[k][1];
            ol[3*k+2] = wz + T[k][2];
        }
    }
    __syncthreads();

    // ---- coalesced float4 store ----
    if (fullTile) {
        float4* g4 = (float4*)(out + tileBase);
        const float4* l4 = (const float4*)lds;
        for (int idx = tid; idx < TILE_V4; idx += BLOCK) g4[idx] = l4[idx];
    } else {
        for (int idx = tid; idx < TILE_F; idx += BLOCK) {
            const long long g = tileBase + idx;
            if (g < totalF) out[g] = lds[idx];
        }
    }
}

extern "C" void kernel_launch(void* const* d_in, const int* in_sizes, int n_in,
                              void* d_out, int out_size, void* d_ws, size_t ws_size,
                              hipStream_t stream)
{
    const float* joints = (const float*)d_in[0];
    const float* tempJ  = (const float*)d_in[1];
    float* out          = (float*)d_out;

    const int n_total = in_sizes[0] / 63;   // (N,21,3) flattened
    const int grid = (n_total + BLOCK - 1) / BLOCK;
    kin_fwd<<<grid, BLOCK, 0, stream>>>(joints, tempJ, out, n_total);
}

// Round 9
// 110.109 us; speedup vs baseline: 1.0882x; 1.0062x over previous
//
#include <hip/hip_runtime.h>
#include <math.h>

#define BLOCK 256
#define HF 63                      // floats per hand
#define TILE_F (BLOCK * HF)        // 16128 floats per tile (64512 B)
#define TILE_V4 (TILE_F / 4)       // 4032 float4s

__device__ __forceinline__ float rsqf(float x)  { return __builtin_amdgcn_rsqf(x); }
__device__ __forceinline__ float sqtf(float x)  { return __builtin_amdgcn_sqrtf(x); }

__global__ __launch_bounds__(BLOCK, 2)
void kin_fwd(const float* __restrict__ joints,
             const float* __restrict__ tempJ,
             float* __restrict__ out,
             int n_total)
{
    constexpr int CHILD[15]  = {2,3,17, 5,6,18, 8,9,20, 11,12,19, 14,15,16};
    constexpr int PARENT[15] = {1,2,3, 4,5,6, 7,8,9, 10,11,12, 13,14,15};
    constexpr int GPID[15]   = {0,1,2, 0,4,5, 0,7,8, 0,10,11, 0,13,14};
    constexpr int PALMNZ[5]  = {1,4,7,10,13};   // palm minus wrist (J[0]=T[0]=0 after centering)

    __shared__ float lds[TILE_F];          // joints tile; reused for output

    const int tid = threadIdx.x;
    const int n   = blockIdx.x * BLOCK + tid;
    const long long tileBase = (long long)blockIdx.x * TILE_F;
    const long long totalF   = (long long)n_total * HF;
    const bool fullTile = (tileBase + TILE_F) <= totalF;
    const bool active = (n < n_total);

    // ---- PHASE 1: joints -> LDS (coalesced float4)  ‖  tempJ -> regs (scalar) ----
    // Both global streams in flight together; one barrier drains everything.
    if (fullTile) {
        const float4* g4 = (const float4*)(joints + tileBase);
        float4* l4 = (float4*)lds;
        for (int idx = tid; idx < TILE_V4; idx += BLOCK) l4[idx] = g4[idx];
    } else {
        for (int idx = tid; idx < TILE_F; idx += BLOCK) {
            const long long g = tileBase + idx;
            lds[idx] = (g < totalF) ? joints[g] : 0.f;
        }
    }

    float T[21][3];
    if (active) {
        const float* tp = tempJ + (long long)n * HF;   // strided scalar loads, overlap staging
#pragma unroll
        for (int k = 0; k < 21; ++k) {
            T[k][0] = tp[3*k+0];
            T[k][1] = tp[3*k+1];
            T[k][2] = tp[3*k+2];
        }
    }
    __syncthreads();   // joints LDS ready; all tempJ loads drained too (vmcnt(0) at barrier)

    float wx = 0.f, wy = 0.f, wz = 0.f;

    if (active) {
        // center template at its wrist
        const float ox = T[0][0], oy = T[0][1], oz = T[0][2];
#pragma unroll
        for (int k = 0; k < 21; ++k) { T[k][0] -= ox; T[k][1] -= oy; T[k][2] -= oz; }

        float blen2[15];           // squared template bone lengths
#pragma unroll
        for (int i = 0; i < 15; ++i) {
            const float dx = T[CHILD[i]][0] - T[PARENT[i]][0];
            const float dy = T[CHILD[i]][1] - T[PARENT[i]][1];
            const float dz = T[CHILD[i]][2] - T[PARENT[i]][2];
            blen2[i] = dx*dx + dy*dy + dz*dz;
        }

        const float* jl = lds + tid * HF;
        wx = jl[0]; wy = jl[1]; wz = jl[2];
        // centered joint accessor (LDS-resident; each element consumed once)
        #define JLC(k,d) (jl[3*(k)+(d)] - ((d)==0 ? wx : ((d)==1 ? wy : wz)))

        // H = sum_palm T[k] * J[k]^T  (wrist term is exactly zero)
        float H[3][3] = {{0.f,0.f,0.f},{0.f,0.f,0.f},{0.f,0.f,0.f}};
#pragma unroll
        for (int p = 0; p < 5; ++p) {
            const int k = PALMNZ[p];
            const float jx = JLC(k,0), jy = JLC(k,1), jz = JLC(k,2);
            H[0][0] += T[k][0]*jx; H[0][1] += T[k][0]*jy; H[0][2] += T[k][0]*jz;
            H[1][0] += T[k][1]*jx; H[1][1] += T[k][1]*jy; H[1][2] += T[k][1]*jz;
            H[2][0] += T[k][2]*jx; H[2][1] += T[k][2]*jy; H[2][2] += T[k][2]*jz;
        }

        // A = H^T H  (symmetric PSD)
        float A[3][3];
#pragma unroll
        for (int i = 0; i < 3; ++i)
#pragma unroll
            for (int j = 0; j < 3; ++j)
                A[i][j] = H[0][i]*H[0][j] + H[1][i]*H[1][j] + H[2][i]*H[2][j];

        // ---- Cardano eigenvalues of A ----
        const float q   = (A[0][0] + A[1][1] + A[2][2]) * (1.f/3.f);
        const float a00 = A[0][0]-q, a11 = A[1][1]-q, a22 = A[2][2]-q;
        const float a01 = A[0][1], a02 = A[0][2], a12 = A[1][2];
        const float p1  = a01*a01 + a02*a02 + a12*a12;
        const float p2s = a00*a00 + a11*a11 + a22*a22 + 2.f*p1;
        const float p26 = p2s*(1.f/6.f) + 1e-30f;
        const float ip  = rsqf(p26);         // 1/p
        const float p   = p26 * ip;          // p = sqrt(p2/6)
        const float detC =
            a00*(a11*a22 - a12*a12) - a01*(a01*a22 - a12*a02) + a02*(a01*a12 - a11*a02);
        float r = 0.5f * detC * ip*ip*ip;
        r = fminf(1.f, fmaxf(-1.f, r));
        const float phi_rev = acosf(r) * 0.05305164769729845f;   // acos(r)/3 in revolutions
        const float cph = __builtin_amdgcn_cosf(phi_rev);
        const float sph = __builtin_amdgcn_sinf(phi_rev);
        const float e1 = q + 2.f*p*cph;                          // largest
        const float e3 = q - p*(cph + 1.7320508075688772f*sph);  // smallest
        const float e2 = 3.f*q - e1 - e3;                        // middle

        // ---- robust eigvec for the MOST ISOLATED eigenvalue ----
        const float gap12 = e1 - e2, gap23 = e2 - e3;
        const bool isoTop = (gap12 >= gap23);
        const float sAB = isoTop ? (e2 + e3) : (e1 + e2);
        const float pAB = isoTop ? (e2 * e3) : (e1 * e2);

        // A2 = A*A (symmetric, 6 entries)
        const float A2_00 = A[0][0]*A[0][0] + A[0][1]*A[0][1] + A[0][2]*A[0][2];
        const float A2_01 = A[0][0]*A[0][1] + A[0][1]*A[1][1] + A[0][2]*A[1][2];
        const float A2_02 = A[0][0]*A[0][2] + A[0][1]*A[1][2] + A[0][2]*A[2][2];
        const float A2_11 = A[0][1]*A[0][1] + A[1][1]*A[1][1] + A[1][2]*A[1][2];
        const float A2_12 = A[0][1]*A[0][2] + A[1][1]*A[1][2] + A[1][2]*A[2][2];
        const float A2_22 = A[0][2]*A[0][2] + A[1][2]*A[1][2] + A[2][2]*A[2][2];

        const float m00 = A2_00 - sAB*A[0][0] + pAB;
        const float m01 = A2_01 - sAB*A[0][1];
        const float m02 = A2_02 - sAB*A[0][2];
        const float m11 = A2_11 - sAB*A[1][1] + pAB;
        const float m12 = A2_12 - sAB*A[1][2];
        const float m22 = A2_22 - sAB*A[2][2] + pAB;

        const float n0c = m00*m00 + m01*m01 + m02*m02;
        const float n1c = m01*m01 + m11*m11 + m12*m12;
        const float n2c = m02*m02 + m12*m12 + m22*m22;
        float vx = m00, vy = m01, vz = m02, nb = n0c;
        if (n1c > nb) { vx = m01; vy = m11; vz = m12; nb = n1c; }
        if (n2c > nb) { vx = m02; vy = m12; vz = m22; }
        if (nb < 1e-24f) { vx = 1.f; vy = 0.f; vz = 0.f; }   // fully-degenerate fallback
        {
            const float invv = rsqf(vx*vx + vy*vy + vz*vz + 1e-35f);
            vx *= invv; vy *= invv; vz *= invv;
        }

        // orthonormal basis (b1,b2) of plane ⊥ v_iso
        float hx, hy, hz;
        {
            const float axv = fabsf(vx), ayv = fabsf(vy), azv = fabsf(vz);
            if (axv <= ayv && axv <= azv)      { hx = 0.f;  hy = vz;  hz = -vy; }
            else if (ayv <= azv)               { hx = -vz;  hy = 0.f; hz = vx;  }
            else                               { hx = vy;   hy = -vx; hz = 0.f; }
        }
        const float invh = rsqf(hx*hx + hy*hy + hz*hz + 1e-35f);
        const float b1x = hx*invh, b1y = hy*invh, b1z = hz*invh;
        const float b2x = vy*b1z - vz*b1y;
        const float b2y = vz*b1x - vx*b1z;
        const float b2z = vx*b1y - vy*b1x;

        // 2x2 restriction of A to the plane: B = [alpha beta; beta gamma]
        const float Ab1x = A[0][0]*b1x + A[0][1]*b1y + A[0][2]*b1z;
        const float Ab1y = A[0][1]*b1x + A[1][1]*b1y + A[1][2]*b1z;
        const float Ab1z = A[0][2]*b1x + A[1][2]*b1y + A[2][2]*b1z;
        const float Ab2x = A[0][0]*b2x + A[0][1]*b2y + A[0][2]*b2z;
        const float Ab2y = A[0][1]*b2x + A[1][1]*b2y + A[1][2]*b2z;
        const float Ab2z = A[0][2]*b2x + A[1][2]*b2y + A[2][2]*b2z;
        const float alpha = b1x*Ab1x + b1y*Ab1y + b1z*Ab1z;
        const float beta  = b2x*Ab1x + b2y*Ab1y + b2z*Ab1z;
        const float gamma = b2x*Ab2x + b2y*Ab2y + b2z*Ab2z;

        // top-of-plane eigenvector: t = (beta, root - dif) in (b1,b2) coords
        const float difq  = 0.5f*(alpha - gamma);
        const float rootq = sqtf(difq*difq + beta*beta);
        float tx = beta, ty = rootq - difq;
        if (tx*tx + ty*ty < 1e-30f) { tx = 1.f; ty = 0.f; }  // degenerate plane: any basis
        const float invt = rsqf(tx*tx + ty*ty + 1e-35f);
        const float ctx = tx*invt, cty = ty*invt;
        const float wpx = ctx*b1x + cty*b2x;
        const float wpy = ctx*b1y + cty*b2y;
        const float wpz = ctx*b1z + cty*b2z;
        // in-plane complement (sign irrelevant: u's inherit v-signs through GS)
        const float wmx = vy*wpz - vz*wpy;
        const float wmy = vz*wpx - vx*wpz;
        const float wmz = vx*wpy - vy*wpx;

        // assign by descending eigenvalue
        const float v1x = isoTop ? vx  : wpx;
        const float v1y = isoTop ? vy  : wpy;
        const float v1z = isoTop ? vz  : wpz;
        const float v2x = isoTop ? wpx : wmx;
        const float v2y = isoTop ? wpy : wmy;
        const float v2z = isoTop ? wpz : wmz;
        // v3 = v1 x v2  (det V = +1 => Kabsch sign folds to +1 with det U = +1)
        const float v3x = v1y*v2z - v1z*v2y;
        const float v3y = v1z*v2x - v1x*v2z;
        const float v3z = v1x*v2y - v1y*v2x;

        // U via Gram-Schmidt on H*V (no 1/sigma anywhere)
        float R[3][3];
        {
            const float w1x = H[0][0]*v1x + H[0][1]*v1y + H[0][2]*v1z;
            const float w1y = H[1][0]*v1x + H[1][1]*v1y + H[1][2]*v1z;
            const float w1z = H[2][0]*v1x + H[2][1]*v1y + H[2][2]*v1z;
            const float in1 = rsqf(w1x*w1x + w1y*w1y + w1z*w1z + 1e-35f);
            const float u1x = w1x*in1, u1y = w1y*in1, u1z = w1z*in1;

            float w2x = H[0][0]*v2x + H[0][1]*v2y + H[0][2]*v2z;
            float w2y = H[1][0]*v2x + H[1][1]*v2y + H[1][2]*v2z;
            float w2z = H[2][0]*v2x + H[2][1]*v2y + H[2][2]*v2z;
            const float dp = u1x*w2x + u1y*w2y + u1z*w2z;
            w2x -= dp*u1x; w2y -= dp*u1y; w2z -= dp*u1z;
            const float in2 = rsqf(w2x*w2x + w2y*w2y + w2z*w2z + 1e-35f);
            const float u2x = w2x*in2, u2y = w2y*in2, u2z = w2z*in2;

            const float u3x = u1y*u2z - u1z*u2y;
            const float u3y = u1z*u2x - u1x*u2z;
            const float u3z = u1x*u2y - u1y*u2x;

            R[0][0] = v1x*u1x + v2x*u2x + v3x*u3x;
            R[0][1] = v1x*u1y + v2x*u2y + v3x*u3y;
            R[0][2] = v1x*u1z + v2x*u2z + v3x*u3z;
            R[1][0] = v1y*u1x + v2y*u2x + v3y*u3x;
            R[1][1] = v1y*u1y + v2y*u2y + v3y*u3y;
            R[1][2] = v1y*u1z + v2y*u2z + v3y*u3z;
            R[2][0] = v1z*u1x + v2z*u2x + v3z*u3x;
            R[2][1] = v1z*u1y + v2z*u2y + v3z*u3y;
            R[2][2] = v1z*u1z + v2z*u2z + v3z*u3z;
        }

        // T = R @ T
#pragma unroll
        for (int k = 0; k < 21; ++k) {
            const float x = T[k][0], y = T[k][1], z = T[k][2];
            T[k][0] = R[0][0]*x + R[0][1]*y + R[0][2]*z;
            T[k][1] = R[1][0]*x + R[1][1]*y + R[1][2]*z;
            T[k][2] = R[2][0]*x + R[2][1]*y + R[2][2]*z;
        }

        // kinematic chain — LEVEL-MAJOR: 5 independent fingers in flight per level
#pragma unroll
        for (int k2 = 0; k2 < 3; ++k2) {
#pragma unroll
            for (int f = 0; f < 5; ++f) {
                const int i = f*3 + k2;
                const int ch = CHILD[i], pa = PARENT[i], gp = GPID[i];

                // bone-length renorm: T[ch] = T[pa] + v1 * sqrt(blen2/d2)
                const float v1xc = JLC(ch,0) - T[pa][0];
                const float v1yc = JLC(ch,1) - T[pa][1];
                const float v1zc = JLC(ch,2) - T[pa][2];
                const float d2  = v1xc*v1xc + v1yc*v1yc + v1zc*v1zc;
                const float b2  = blen2[i];
                const float sc  = b2 * rsqf(b2*d2 + 1e-30f);   // sqrt(b2)/sqrt(d2)
                const float vbx = v1xc*sc, vby = v1yc*sc, vbz = v1zc*sc;

                const float v0x = T[pa][0] - T[gp][0];
                const float v0y = T[pa][1] - T[gp][1];
                const float v0z = T[pa][2] - T[gp][2];

                const float crx = v0y*vbz - v0z*vby;
                const float cry = v0z*vbx - v0x*vbz;
                const float crz = v0x*vby - v0y*vbx;
                const float s2  = crx*crx + cry*cry + crz*crz;
                const float c   = v0x*vbx + v0y*vby + v0z*vbz;

                // delta = clip(ang,0,pi/2) - ang; nonzero only when c < 0
                const float invr  = rsqf(s2 + c*c + 1e-35f);
                const float sainv = rsqf(s2 + 1e-35f);
                const float s     = s2 * sainv;              // sqrt(s2)
                const float cosd  = (c < 0.f) ? s*invr : 1.f;
                const float sind  = (c < 0.f) ? c*invr : 0.f;

                const float ax = crx*sainv, ay = cry*sainv, az = crz*sainv;
                const float cxx = ay*vbz - az*vby;
                const float cxy = az*vbx - ax*vbz;
                const float cxz = ax*vby - ay*vbx;
                // axis . vb == 0 exactly (axis ∝ v0 x vb) -> omc term dropped
                T[ch][0] = vbx*cosd + cxx*sind + T[pa][0];
                T[ch][1] = vby*cosd + cxy*sind + T[pa][1];
                T[ch][2] = vbz*cosd + cxz*sind + T[pa][2];
            }
        }
        #undef JLC

        // write own result region (this thread's JLC reads of this region are done)
        float* ol = lds + tid * HF;
#pragma unroll
        for (int k = 0; k < 21; ++k) {
            ol[3*k+0] = wx + T[k][0];
            ol[3*k+1] = wy + T[k][1];
            ol[3*k+2] = wz + T[k][2];
        }
    }
    __syncthreads();

    // ---- PHASE 2: coalesced float4 store ----
    if (fullTile) {
        float4* g4 = (float4*)(out + tileBase);
        const float4* l4 = (const float4*)lds;
        for (int idx = tid; idx < TILE_V4; idx += BLOCK) g4[idx] = l4[idx];
    } else {
        for (int idx = tid; idx < TILE_F; idx += BLOCK) {
            const long long g = tileBase + idx;
            if (g < totalF) out[g] = lds[idx];
        }
    }
}

extern "C" void kernel_launch(void* const* d_in, const int* in_sizes, int n_in,
                              void* d_out, int out_size, void* d_ws, size_t ws_size,
                              hipStream_t stream)
{
    const float* joints = (const float*)d_in[0];
    const float* tempJ  = (const float*)d_in[1];
    float* out          = (float*)d_out;

    const int n_total = in_sizes[0] / 63;   // (N,21,3) flattened
    const int grid = (n_total + BLOCK - 1) / BLOCK;
    kin_fwd<<<grid, BLOCK, 0, stream>>>(joints, tempJ, out, n_total);
}